// Round 7
// baseline (442.522 us; speedup 1.0000x reference)
//
#include <hip/hip_runtime.h>

#define NN 100000
#define NE 3200000
#define D  128
#define NBUCK 782               // buckets of 128 dst nodes (dst>>7)
#define EPB 2048                // edges per count/scatter block
#define NBLK ((NE + EPB - 1) / EPB)   // 1563

typedef __attribute__((ext_vector_type(8))) short bf16x8;
typedef __attribute__((ext_vector_type(4))) float f32x4;
typedef __attribute__((ext_vector_type(2))) float f32x2;

__device__ __forceinline__ float bf2f(unsigned int u) {      // u = bf16 bits
    union { unsigned int i; float f; } v; v.i = u << 16; return v.f;
}
__device__ __forceinline__ float bits2f(unsigned int u) {    // raw f32 bits
    union { unsigned int i; float f; } v; v.i = u; return v.f;
}
__device__ __forceinline__ unsigned int f2bf(float f) {      // RNE bf16
    union { float f; unsigned int i; } v; v.f = f;
    unsigned int u = v.i;
    return (u + 0x7fffu + ((u >> 16) & 1u)) >> 16;
}

// --- 0. zero gcnt + detect edge_index width (int64 -> odd int32 slots all zero) ---
__global__ __launch_bounds__(1024) void zero_detect_kernel(const int* __restrict__ ei,
        int* __restrict__ flag, int* __restrict__ gcnt) {
    int t = threadIdx.x;
    if (t < NBUCK) gcnt[t] = 0;
    if (t < 64) {
        int v = ei[2 * t + 1];
        unsigned long long ball = __ballot(v != 0);
        if (t == 0) flag[0] = (ball == 0ull) ? 1 : 0;   // 1 => int64
    }
}

// --- 1. coarse count: per-block LDS hist over 782 buckets; returned atomic = block base ---
__global__ __launch_bounds__(256) void count1_kernel(const int* __restrict__ ei,
        int* __restrict__ gcnt, unsigned short* __restrict__ blockbase,
        const int* __restrict__ flag) {
    __shared__ int h[NBUCK];
    int t = threadIdx.x, b = blockIdx.x;
    int s = flag[0];
    for (int j = t; j < NBUCK; j += 256) h[j] = 0;
    __syncthreads();
    long e0 = (long)b * EPB;
#pragma unroll
    for (int it = 0; it < EPB / 256; ++it) {
        long e = e0 + it * 256 + t;
        if (e < NE) {
            int d = s ? (int)((const long*)ei)[NE + e] : ei[NE + e];
            atomicAdd(&h[d >> 7], 1);
        }
    }
    __syncthreads();
    for (int j = t; j < NBUCK; j += 256) {
        int v = h[j];
        unsigned short bb = 0;
        if (v) bb = (unsigned short)atomicAdd(&gcnt[j], v);   // bucket total < 65536
        blockbase[(size_t)b * NBUCK + j] = bb;
    }
}

// --- 2. one-block exclusive scan of bucket counts -> gbase ---
__global__ __launch_bounds__(1024) void scanb_kernel(const int* __restrict__ gcnt,
        int* __restrict__ gbase) {
    __shared__ int s[1024];
    int t = threadIdx.x;
    s[t] = (t < NBUCK) ? gcnt[t] : 0;
    __syncthreads();
    for (int off = 1; off < 1024; off <<= 1) {
        int v = (t >= off) ? s[t - off] : 0;
        __syncthreads();
        s[t] += v;
        __syncthreads();
    }
    if (t < NBUCK) gbase[t] = (t > 0) ? s[t - 1] : 0;
    if (t == 0) gbase[NBUCK] = NE;
}

// --- 3. scatter edges into bucket-contiguous tmp (u64: dlow<<32 | csr-word) ---
__global__ __launch_bounds__(256) void scatter1_kernel(const int* __restrict__ ei,
        const float* __restrict__ ew, const int* __restrict__ gbase,
        const unsigned short* __restrict__ blockbase, const int* __restrict__ flag,
        unsigned long long* __restrict__ tmp) {
    __shared__ int gb[NBUCK];
    __shared__ unsigned short bbs[NBUCK];
    __shared__ int cur[NBUCK];
    int t = threadIdx.x, b = blockIdx.x;
    int s = flag[0];
    for (int j = t; j < NBUCK; j += 256) {
        gb[j] = gbase[j];
        bbs[j] = blockbase[(size_t)b * NBUCK + j];
        cur[j] = 0;
    }
    __syncthreads();
    long e0 = (long)b * EPB;
#pragma unroll
    for (int it = 0; it < EPB / 256; ++it) {
        long e = e0 + it * 256 + t;
        if (e < NE) {
            int src, dst;
            if (s) { src = (int)((const long*)ei)[e]; dst = (int)((const long*)ei)[NE + e]; }
            else   { src = ei[e];                     dst = ei[NE + e]; }
            float w = ew[e];
            int bkt = dst >> 7, dlow = dst & 127;
            int r = atomicAdd(&cur[bkt], 1);
            unsigned int word = ((unsigned int)src << 15) | (f2bf(w) >> 1);
            tmp[gb[bkt] + (int)bbs[bkt] + r] =
                ((unsigned long long)(unsigned int)dlow << 32) | word;
        }
    }
}

// --- 4. per-bucket: 128-slot LDS hist(+wsum) + scan -> row_ptr & dis; scatter -> csr ---
__global__ __launch_bounds__(256) void build2_kernel(const unsigned long long* __restrict__ tmp,
        const int* __restrict__ gbase, int* __restrict__ row_ptr, unsigned int* __restrict__ csr,
        float* __restrict__ dis) {
    __shared__ int hist[128], excl[128], cur[128];
    __shared__ float wsum[128];
    int t = threadIdx.x, k = blockIdx.x;
    int base = gbase[k], endb = gbase[k + 1];
    if (t < 128) { hist[t] = 0; cur[t] = 0; wsum[t] = 0.f; }
    __syncthreads();
    for (int i = base + t; i < endb; i += 256) {
        unsigned long long v = tmp[i];
        int dl = (int)(v >> 32);
        atomicAdd(&hist[dl], 1);
        atomicAdd(&wsum[dl], bf2f(((unsigned int)v & 0x7fffu) << 1));
    }
    __syncthreads();
    if (t < 128) excl[t] = hist[t];
    __syncthreads();
    for (int off = 1; off < 128; off <<= 1) {        // inclusive scan over 128
        int v = (t >= off && t < 128) ? excl[t - off] : 0;
        __syncthreads();
        if (t < 128) excl[t] += v;
        __syncthreads();
    }
    if (t < 128) {
        int ex = excl[t] - hist[t];                  // exclusive
        int node = k * 128 + t;
        if (node < NN) {
            row_ptr[node] = base + ex;
            dis[node] = rsqrtf(1.0f + wsum[t]);      // self-loop weight 1 included
        }
        if (node == NN - 1) row_ptr[NN] = NE;
        excl[t] = ex;
    }
    __syncthreads();
    for (int i = base + t; i < endb; i += 256) {
        unsigned long long v = tmp[i];
        int dl = (int)(v >> 32);
        int r = atomicAdd(&cur[dl], 1);
        csr[base + excl[dl] + r] = (unsigned int)v;
    }
}

// --- 5. h' = bf16(dis[row] * (x @ W)): prescaled rows kill the per-edge dis[src] gather ---
__global__ __launch_bounds__(256) void mgemm_kernel(const float* __restrict__ x,
        const float* __restrict__ W, const float* __restrict__ dis,
        unsigned short* __restrict__ hb) {
    __shared__ unsigned short WT[16 * 128 * 8];    // 32 KB
    int t = threadIdx.x;
    {
        int n = t & 127, half = t >> 7;
        for (int it = 0; it < 8; ++it) {
            int kb = half * 8 + it;                // k-chunk 0..15
            union { unsigned short s[8]; uint4 v; } pk;
#pragma unroll
            for (int j = 0; j < 8; ++j)
                pk.s[j] = (unsigned short)f2bf(W[(kb * 8 + j) * D + n]);
            *(uint4*)&WT[(kb * 128 + n) * 8] = pk.v;
        }
    }
    __syncthreads();
    int l = t & 63, w = t >> 6;
    int q = l >> 4, m = l & 15;
    long mbase = (long)blockIdx.x * 128 + w * 32;
    long r0 = mbase + m;      if (r0 > NN - 1) r0 = NN - 1;   // clamp: no OOB reads
    long r1 = mbase + 16 + m; if (r1 > NN - 1) r1 = NN - 1;
    const float* a0p = x + r0 * D + q * 8;
    const float* a1p = x + r1 * D + q * 8;
    f32x4 acc[2][8];
#pragma unroll
    for (int mt = 0; mt < 2; ++mt)
#pragma unroll
        for (int nt = 0; nt < 8; ++nt) acc[mt][nt] = (f32x4){0.f, 0.f, 0.f, 0.f};
#pragma unroll
    for (int kc = 0; kc < 4; ++kc) {
        float4 va0 = *(const float4*)(a0p + kc * 32);
        float4 va1 = *(const float4*)(a0p + kc * 32 + 4);
        float4 vb0 = *(const float4*)(a1p + kc * 32);
        float4 vb1 = *(const float4*)(a1p + kc * 32 + 4);
        union { unsigned short s[8]; bf16x8 v; } ua, ub;
        ua.s[0] = (unsigned short)f2bf(va0.x); ua.s[1] = (unsigned short)f2bf(va0.y);
        ua.s[2] = (unsigned short)f2bf(va0.z); ua.s[3] = (unsigned short)f2bf(va0.w);
        ua.s[4] = (unsigned short)f2bf(va1.x); ua.s[5] = (unsigned short)f2bf(va1.y);
        ua.s[6] = (unsigned short)f2bf(va1.z); ua.s[7] = (unsigned short)f2bf(va1.w);
        ub.s[0] = (unsigned short)f2bf(vb0.x); ub.s[1] = (unsigned short)f2bf(vb0.y);
        ub.s[2] = (unsigned short)f2bf(vb0.z); ub.s[3] = (unsigned short)f2bf(vb0.w);
        ub.s[4] = (unsigned short)f2bf(vb1.x); ub.s[5] = (unsigned short)f2bf(vb1.y);
        ub.s[6] = (unsigned short)f2bf(vb1.z); ub.s[7] = (unsigned short)f2bf(vb1.w);
        const bf16x8* bp = (const bf16x8*)WT + (kc * 4 + q) * 128 + m;
#pragma unroll
        for (int nt = 0; nt < 8; ++nt) {
            bf16x8 bfr = bp[nt * 16];
            acc[0][nt] = __builtin_amdgcn_mfma_f32_16x16x32_bf16(ua.v, bfr, acc[0][nt], 0, 0, 0);
            acc[1][nt] = __builtin_amdgcn_mfma_f32_16x16x32_bf16(ub.v, bfr, acc[1][nt], 0, 0, 0);
        }
    }
#pragma unroll
    for (int mt = 0; mt < 2; ++mt) {
        long rowbase = mbase + mt * 16;
#pragma unroll
        for (int r = 0; r < 4; ++r) {
            long row = rowbase + q * 4 + r;          // C/D: col=lane&15, row=quad*4+reg
            float dsc = dis[(row < NN) ? row : (NN - 1)];
#pragma unroll
            for (int nt = 0; nt < 8; ++nt)
                if (row < NN)
                    hb[row * D + nt * 16 + m] = (unsigned short)f2bf(acc[mt][nt][r] * dsc);
        }
    }
}

// --- 6. pull: out = dn*(sum w*h'[src] + h'[n]) + bias ; one wave/node, 8 gathers in flight ---
__global__ __launch_bounds__(256) void pull_kernel(const unsigned int* __restrict__ hb,
        const float* __restrict__ dis, const int* __restrict__ row_ptr,
        const unsigned int* __restrict__ csr, const float2* __restrict__ bias2,
        float* __restrict__ out) {
    int t = blockIdx.x * 256 + threadIdx.x;
    int n = t >> 6, l = t & 63;
    float dn = dis[n];
    unsigned int a = hb[n * 64 + l];                 // self term h'[n]
    float accx = bits2f(a << 16);
    float accy = bits2f(a & 0xffff0000u);
    int e = row_ptr[n], end = row_ptr[n + 1];
    for (; e + 7 < end; e += 8) {                    // 8 independent row-gathers in flight
        unsigned int c[8];
#pragma unroll
        for (int j = 0; j < 8; ++j) c[j] = __builtin_nontemporal_load(csr + e + j);
        int s_[8];
#pragma unroll
        for (int j = 0; j < 8; ++j) s_[j] = c[j] >> 15;
        unsigned int u[8];
#pragma unroll
        for (int j = 0; j < 8; ++j) u[j] = hb[s_[j] * 64 + l];
#pragma unroll
        for (int j = 0; j < 8; ++j) {
            float m = bits2f(c[j] << 17);            // w decode = 1 shift
            accx += bits2f(u[j] << 16) * m;
            accy += bits2f(u[j] & 0xffff0000u) * m;
        }
    }
    for (; e + 1 < end; e += 2) {
        unsigned int c0 = __builtin_nontemporal_load(csr + e);
        unsigned int c1 = __builtin_nontemporal_load(csr + e + 1);
        int s0 = c0 >> 15, s1 = c1 >> 15;
        unsigned int u0 = hb[s0 * 64 + l];
        unsigned int u1 = hb[s1 * 64 + l];
        float m0 = bits2f(c0 << 17), m1 = bits2f(c1 << 17);
        accx += bits2f(u0 << 16) * m0; accy += bits2f(u0 & 0xffff0000u) * m0;
        accx += bits2f(u1 << 16) * m1; accy += bits2f(u1 & 0xffff0000u) * m1;
    }
    if (e < end) {
        unsigned int c0 = __builtin_nontemporal_load(csr + e);
        int s0 = c0 >> 15;
        unsigned int u0 = hb[s0 * 64 + l];
        float m0 = bits2f(c0 << 17);
        accx += bits2f(u0 << 16) * m0; accy += bits2f(u0 & 0xffff0000u) * m0;
    }
    float2 bv = bias2[l];
    f32x2 r;
    r.x = accx * dn + bv.x;
    r.y = accy * dn + bv.y;
    __builtin_nontemporal_store(r, (f32x2*)out + ((size_t)n * 64 + l));
}

extern "C" void kernel_launch(void* const* d_in, const int* in_sizes, int n_in,
                              void* d_out, int out_size, void* d_ws, size_t ws_size,
                              hipStream_t stream) {
    const float* x  = (const float*)d_in[0];
    const int*   ei = (const int*)d_in[1];
    const float* ew = (const float*)d_in[2];
    const float* W  = (const float*)d_in[3];
    const float* b  = (const float*)d_in[4];
    float* out = (float*)d_out;

    // workspace (~42 MB). tmp (bucketed edges) and hb (GEMM output) are
    // non-overlapping in TIME (build2 reads tmp before mgemm writes hb) -> aliased.
    unsigned long long* tmp = (unsigned long long*)d_ws;           // NE u64 (25.6 MB)
    unsigned short*     hb  = (unsigned short*)d_ws;               // NN*128 bf16 (25.6 MB)
    unsigned int*       csr = (unsigned int*)((char*)d_ws + (size_t)NE * 8);  // NE u32
    float*              dis = (float*)(csr + NE);                  // NN
    int*            row_ptr = (int*)(dis + NN);                    // NN+1
    int*            gcnt    = row_ptr + NN + 1;                    // NBUCK
    int*            gbase   = gcnt + NBUCK;                        // NBUCK+1
    int*            flag    = gbase + NBUCK + 1;                   // 1
    unsigned short* blockbase = (unsigned short*)(flag + 1);       // NBLK*NBUCK u16 (2.4 MB)

    zero_detect_kernel<<<1, 1024, 0, stream>>>(ei, flag, gcnt);
    count1_kernel<<<NBLK, 256, 0, stream>>>(ei, gcnt, blockbase, flag);
    scanb_kernel<<<1, 1024, 0, stream>>>(gcnt, gbase);
    scatter1_kernel<<<NBLK, 256, 0, stream>>>(ei, ew, gbase, blockbase, flag, tmp);
    build2_kernel<<<NBUCK, 256, 0, stream>>>(tmp, gbase, row_ptr, csr, dis);
    mgemm_kernel<<<(NN + 127) / 128, 256, 0, stream>>>(x, W, dis, hb);
    pull_kernel<<<(NN * 64) / 256, 256, 0, stream>>>((const unsigned int*)hb, dis, row_ptr, csr,
                                                     (const float2*)b, (float*)out);
}

// Round 8
// 374.535 us; speedup vs baseline: 1.1815x; 1.1815x over previous
//
#include <hip/hip_runtime.h>

#define NN 100000
#define NE 3200000
#define D  128
#define NBUCK 391               // coarse buckets of 256 dst nodes (dst>>8)
#define EPB 8192                // edges per count/scatter block
#define NBLK ((NE + EPB - 1) / EPB)   // 391
#define BCAP 9216               // build2 LDS segment capacity (avg 8192 + >10 sigma)

typedef __attribute__((ext_vector_type(8))) short bf16x8;
typedef __attribute__((ext_vector_type(4))) float f32x4;
typedef __attribute__((ext_vector_type(2))) float f32x2;

__device__ __forceinline__ float bf2f(unsigned int u) {      // u = bf16 bits
    union { unsigned int i; float f; } v; v.i = u << 16; return v.f;
}
__device__ __forceinline__ float bits2f(unsigned int u) {    // raw f32 bits
    union { unsigned int i; float f; } v; v.i = u; return v.f;
}
__device__ __forceinline__ unsigned int f2bf(float f) {      // RNE bf16
    union { float f; unsigned int i; } v; v.f = f;
    unsigned int u = v.i;
    return (u + 0x7fffu + ((u >> 16) & 1u)) >> 16;
}

// --- 0. zero gcnt + detect edge_index width (int64 -> odd int32 slots all zero) ---
__global__ __launch_bounds__(512) void zero_detect_kernel(const int* __restrict__ ei,
        int* __restrict__ flag, int* __restrict__ gcnt) {
    int t = threadIdx.x;
    if (t < NBUCK) gcnt[t] = 0;
    if (t < 64) {
        int v = ei[2 * t + 1];
        unsigned long long ball = __ballot(v != 0);
        if (t == 0) flag[0] = (ball == 0ull) ? 1 : 0;   // 1 => int64
    }
}

// --- 1. coarse count: per-block LDS hist over 391 buckets; returned atomic = block base ---
__global__ __launch_bounds__(256) void count1_kernel(const int* __restrict__ ei,
        int* __restrict__ gcnt, unsigned short* __restrict__ blockbase,
        const int* __restrict__ flag) {
    __shared__ int h[NBUCK];
    int t = threadIdx.x, b = blockIdx.x;
    int s = flag[0];
    for (int j = t; j < NBUCK; j += 256) h[j] = 0;
    __syncthreads();
    long e0 = (long)b * EPB;
#pragma unroll
    for (int it = 0; it < EPB / 256; ++it) {
        long e = e0 + it * 256 + t;
        if (e < NE) {
            int d = s ? (int)((const long*)ei)[NE + e] : ei[NE + e];
            atomicAdd(&h[d >> 8], 1);
        }
    }
    __syncthreads();
    for (int j = t; j < NBUCK; j += 256) {
        int bb = atomicAdd(&gcnt[j], h[j]);          // bucket total ~8.5K << 65536
        blockbase[(size_t)b * NBUCK + j] = (unsigned short)bb;
    }
}

// --- 2. one-block exclusive scan of bucket counts -> gbase ---
__global__ __launch_bounds__(512) void scanb_kernel(const int* __restrict__ gcnt,
        int* __restrict__ gbase) {
    __shared__ int s[512];
    int t = threadIdx.x;
    s[t] = (t < NBUCK) ? gcnt[t] : 0;
    __syncthreads();
    for (int off = 1; off < 512; off <<= 1) {
        int v = (t >= off) ? s[t - off] : 0;
        __syncthreads();
        s[t] += v;
        __syncthreads();
    }
    if (t < NBUCK) gbase[t] = (t > 0) ? s[t - 1] : 0;
    if (t == 0) gbase[NBUCK] = NE;
}

// --- 3. scatter edges into bucket-contiguous tmp (u64: dlow<<32 | csr-word) ---
__global__ __launch_bounds__(256) void scatter1_kernel(const int* __restrict__ ei,
        const float* __restrict__ ew, const int* __restrict__ gbase,
        const unsigned short* __restrict__ blockbase, const int* __restrict__ flag,
        unsigned long long* __restrict__ tmp) {
    __shared__ int gb[NBUCK];
    __shared__ unsigned short bbs[NBUCK];
    __shared__ int cur[NBUCK];
    int t = threadIdx.x, b = blockIdx.x;
    int s = flag[0];
    for (int j = t; j < NBUCK; j += 256) {
        gb[j] = gbase[j];
        bbs[j] = blockbase[(size_t)b * NBUCK + j];
        cur[j] = 0;
    }
    __syncthreads();
    long e0 = (long)b * EPB;
#pragma unroll
    for (int it = 0; it < EPB / 256; ++it) {
        long e = e0 + it * 256 + t;
        if (e < NE) {
            int src, dst;
            if (s) { src = (int)((const long*)ei)[e]; dst = (int)((const long*)ei)[NE + e]; }
            else   { src = ei[e];                     dst = ei[NE + e]; }
            float w = ew[e];
            int bkt = dst >> 8, dlow = dst & 255;
            int r = atomicAdd(&cur[bkt], 1);
            unsigned int word = ((unsigned int)src << 15) | (f2bf(w) >> 1);
            tmp[gb[bkt] + (int)bbs[bkt] + r] =
                ((unsigned long long)(unsigned int)dlow << 32) | word;
        }
    }
}

// --- 4. per-bucket: stage segment in LDS; 256-slot hist(+wsum) + scan -> row_ptr & dis;
//        scatter -> csr. Single global read of tmp. ---
__global__ __launch_bounds__(256) void build2_kernel(const unsigned long long* __restrict__ tmp,
        const int* __restrict__ gbase, int* __restrict__ row_ptr, unsigned int* __restrict__ csr,
        float* __restrict__ dis) {
    __shared__ unsigned long long seg[BCAP];         // 73.7 KB
    __shared__ int hist[256], excl[256], cur[256];
    __shared__ float wsum[256];
    int t = threadIdx.x, k = blockIdx.x;
    int base = gbase[k], endb = gbase[k + 1];
    int cnt = endb - base;
    hist[t] = 0; cur[t] = 0; wsum[t] = 0.f;
    __syncthreads();
    if (cnt <= BCAP) {                               // fast path: LDS-staged
        for (int i = t; i < cnt; i += 256) {
            unsigned long long v = tmp[base + i];
            seg[i] = v;
            int dl = (int)(v >> 32);
            atomicAdd(&hist[dl], 1);
            atomicAdd(&wsum[dl], bf2f(((unsigned int)v & 0x7fffu) << 1));
        }
    } else {                                         // overflow fallback (never expected)
        for (int i = base + t; i < endb; i += 256) {
            unsigned long long v = tmp[i];
            int dl = (int)(v >> 32);
            atomicAdd(&hist[dl], 1);
            atomicAdd(&wsum[dl], bf2f(((unsigned int)v & 0x7fffu) << 1));
        }
    }
    __syncthreads();
    excl[t] = hist[t];
    __syncthreads();
    for (int off = 1; off < 256; off <<= 1) {        // inclusive scan
        int v = (t >= off) ? excl[t - off] : 0;
        __syncthreads();
        excl[t] += v;
        __syncthreads();
    }
    int ex = excl[t] - hist[t];                      // exclusive
    int node = k * 256 + t;
    if (node < NN) {
        row_ptr[node] = base + ex;
        dis[node] = rsqrtf(1.0f + wsum[t]);          // self-loop weight 1 included
    }
    if (node == NN - 1) row_ptr[NN] = NE;
    __syncthreads();
    excl[t] = ex;
    __syncthreads();
    if (cnt <= BCAP) {
        for (int i = t; i < cnt; i += 256) {
            unsigned long long v = seg[i];
            int dl = (int)(v >> 32);
            int r = atomicAdd(&cur[dl], 1);
            csr[base + excl[dl] + r] = (unsigned int)v;
        }
    } else {
        for (int i = base + t; i < endb; i += 256) {
            unsigned long long v = tmp[i];
            int dl = (int)(v >> 32);
            int r = atomicAdd(&cur[dl], 1);
            csr[base + excl[dl] + r] = (unsigned int)v;
        }
    }
}

// --- 5. h' = bf16(dis[row] * (x @ W)): prescaled rows kill the per-edge dis[src] gather ---
__global__ __launch_bounds__(256) void mgemm_kernel(const float* __restrict__ x,
        const float* __restrict__ W, const float* __restrict__ dis,
        unsigned short* __restrict__ hb) {
    __shared__ unsigned short WT[16 * 128 * 8];    // 32 KB
    int t = threadIdx.x;
    {
        int n = t & 127, half = t >> 7;
        for (int it = 0; it < 8; ++it) {
            int kb = half * 8 + it;                // k-chunk 0..15
            union { unsigned short s[8]; uint4 v; } pk;
#pragma unroll
            for (int j = 0; j < 8; ++j)
                pk.s[j] = (unsigned short)f2bf(W[(kb * 8 + j) * D + n]);
            *(uint4*)&WT[(kb * 128 + n) * 8] = pk.v;
        }
    }
    __syncthreads();
    int l = t & 63, w = t >> 6;
    int q = l >> 4, m = l & 15;
    long mbase = (long)blockIdx.x * 128 + w * 32;
    long r0 = mbase + m;      if (r0 > NN - 1) r0 = NN - 1;   // clamp: no OOB reads
    long r1 = mbase + 16 + m; if (r1 > NN - 1) r1 = NN - 1;
    const float* a0p = x + r0 * D + q * 8;
    const float* a1p = x + r1 * D + q * 8;
    f32x4 acc[2][8];
#pragma unroll
    for (int mt = 0; mt < 2; ++mt)
#pragma unroll
        for (int nt = 0; nt < 8; ++nt) acc[mt][nt] = (f32x4){0.f, 0.f, 0.f, 0.f};
#pragma unroll
    for (int kc = 0; kc < 4; ++kc) {
        float4 va0 = *(const float4*)(a0p + kc * 32);
        float4 va1 = *(const float4*)(a0p + kc * 32 + 4);
        float4 vb0 = *(const float4*)(a1p + kc * 32);
        float4 vb1 = *(const float4*)(a1p + kc * 32 + 4);
        union { unsigned short s[8]; bf16x8 v; } ua, ub;
        ua.s[0] = (unsigned short)f2bf(va0.x); ua.s[1] = (unsigned short)f2bf(va0.y);
        ua.s[2] = (unsigned short)f2bf(va0.z); ua.s[3] = (unsigned short)f2bf(va0.w);
        ua.s[4] = (unsigned short)f2bf(va1.x); ua.s[5] = (unsigned short)f2bf(va1.y);
        ua.s[6] = (unsigned short)f2bf(va1.z); ua.s[7] = (unsigned short)f2bf(va1.w);
        ub.s[0] = (unsigned short)f2bf(vb0.x); ub.s[1] = (unsigned short)f2bf(vb0.y);
        ub.s[2] = (unsigned short)f2bf(vb0.z); ub.s[3] = (unsigned short)f2bf(vb0.w);
        ub.s[4] = (unsigned short)f2bf(vb1.x); ub.s[5] = (unsigned short)f2bf(vb1.y);
        ub.s[6] = (unsigned short)f2bf(vb1.z); ub.s[7] = (unsigned short)f2bf(vb1.w);
        const bf16x8* bp = (const bf16x8*)WT + (kc * 4 + q) * 128 + m;
#pragma unroll
        for (int nt = 0; nt < 8; ++nt) {
            bf16x8 bfr = bp[nt * 16];
            acc[0][nt] = __builtin_amdgcn_mfma_f32_16x16x32_bf16(ua.v, bfr, acc[0][nt], 0, 0, 0);
            acc[1][nt] = __builtin_amdgcn_mfma_f32_16x16x32_bf16(ub.v, bfr, acc[1][nt], 0, 0, 0);
        }
    }
#pragma unroll
    for (int mt = 0; mt < 2; ++mt) {
        long rowbase = mbase + mt * 16;
#pragma unroll
        for (int r = 0; r < 4; ++r) {
            long row = rowbase + q * 4 + r;          // C/D: col=lane&15, row=quad*4+reg
            float dsc = dis[(row < NN) ? row : (NN - 1)];
#pragma unroll
            for (int nt = 0; nt < 8; ++nt)
                if (row < NN)
                    hb[row * D + nt * 16 + m] = (unsigned short)f2bf(acc[mt][nt][r] * dsc);
        }
    }
}

// --- 6. pull: out = dn*(sum w*h'[src] + h'[n]) + bias ; one wave/node, 8 gathers in flight ---
__global__ __launch_bounds__(256) void pull_kernel(const unsigned int* __restrict__ hb,
        const float* __restrict__ dis, const int* __restrict__ row_ptr,
        const unsigned int* __restrict__ csr, const float2* __restrict__ bias2,
        float* __restrict__ out) {
    int t = blockIdx.x * 256 + threadIdx.x;
    int n = t >> 6, l = t & 63;
    float dn = dis[n];
    unsigned int a = hb[n * 64 + l];                 // self term h'[n]
    float accx = bits2f(a << 16);
    float accy = bits2f(a & 0xffff0000u);
    int e = row_ptr[n], end = row_ptr[n + 1];
    for (; e + 7 < end; e += 8) {                    // 8 independent row-gathers in flight
        unsigned int c[8];
#pragma unroll
        for (int j = 0; j < 8; ++j) c[j] = __builtin_nontemporal_load(csr + e + j);
        int s_[8];
#pragma unroll
        for (int j = 0; j < 8; ++j) s_[j] = c[j] >> 15;
        unsigned int u[8];
#pragma unroll
        for (int j = 0; j < 8; ++j) u[j] = hb[s_[j] * 64 + l];
#pragma unroll
        for (int j = 0; j < 8; ++j) {
            float m = bits2f(c[j] << 17);            // w decode = 1 shift
            accx += bits2f(u[j] << 16) * m;
            accy += bits2f(u[j] & 0xffff0000u) * m;
        }
    }
    for (; e + 1 < end; e += 2) {
        unsigned int c0 = __builtin_nontemporal_load(csr + e);
        unsigned int c1 = __builtin_nontemporal_load(csr + e + 1);
        int s0 = c0 >> 15, s1 = c1 >> 15;
        unsigned int u0 = hb[s0 * 64 + l];
        unsigned int u1 = hb[s1 * 64 + l];
        float m0 = bits2f(c0 << 17), m1 = bits2f(c1 << 17);
        accx += bits2f(u0 << 16) * m0; accy += bits2f(u0 & 0xffff0000u) * m0;
        accx += bits2f(u1 << 16) * m1; accy += bits2f(u1 & 0xffff0000u) * m1;
    }
    if (e < end) {
        unsigned int c0 = __builtin_nontemporal_load(csr + e);
        int s0 = c0 >> 15;
        unsigned int u0 = hb[s0 * 64 + l];
        float m0 = bits2f(c0 << 17);
        accx += bits2f(u0 << 16) * m0; accy += bits2f(u0 & 0xffff0000u) * m0;
    }
    float2 bv = bias2[l];
    f32x2 r;
    r.x = accx * dn + bv.x;
    r.y = accy * dn + bv.y;
    __builtin_nontemporal_store(r, (f32x2*)out + ((size_t)n * 64 + l));
}

extern "C" void kernel_launch(void* const* d_in, const int* in_sizes, int n_in,
                              void* d_out, int out_size, void* d_ws, size_t ws_size,
                              hipStream_t stream) {
    const float* x  = (const float*)d_in[0];
    const int*   ei = (const int*)d_in[1];
    const float* ew = (const float*)d_in[2];
    const float* W  = (const float*)d_in[3];
    const float* b  = (const float*)d_in[4];
    float* out = (float*)d_out;

    // workspace (~40 MB). tmp (bucketed edges) and hb (GEMM output) are
    // non-overlapping in TIME (build2 reads tmp before mgemm writes hb) -> aliased.
    unsigned long long* tmp = (unsigned long long*)d_ws;           // NE u64 (25.6 MB)
    unsigned short*     hb  = (unsigned short*)d_ws;               // NN*128 bf16 (25.6 MB)
    unsigned int*       csr = (unsigned int*)((char*)d_ws + (size_t)NE * 8);  // NE u32
    float*              dis = (float*)(csr + NE);                  // NN
    int*            row_ptr = (int*)(dis + NN);                    // NN+1
    int*            gcnt    = row_ptr + NN + 1;                    // NBUCK
    int*            gbase   = gcnt + NBUCK;                        // NBUCK+1
    int*            flag    = gbase + NBUCK + 1;                   // 1
    unsigned short* blockbase = (unsigned short*)(flag + 1);       // NBLK*NBUCK u16 (306 KB)

    zero_detect_kernel<<<1, 512, 0, stream>>>(ei, flag, gcnt);
    count1_kernel<<<NBLK, 256, 0, stream>>>(ei, gcnt, blockbase, flag);
    scanb_kernel<<<1, 512, 0, stream>>>(gcnt, gbase);
    scatter1_kernel<<<NBLK, 256, 0, stream>>>(ei, ew, gbase, blockbase, flag, tmp);
    build2_kernel<<<NBUCK, 256, 0, stream>>>(tmp, gbase, row_ptr, csr, dis);
    mgemm_kernel<<<(NN + 127) / 128, 256, 0, stream>>>(x, W, dis, hb);
    pull_kernel<<<(NN * 64) / 256, 256, 0, stream>>>((const unsigned int*)hb, dis, row_ptr, csr,
                                                     (const float2*)b, (float*)out);
}